// Round 10
// baseline (196.769 us; speedup 1.0000x reference)
//
#include <hip/hip_runtime.h>
#include <math.h>

// ---------------------------------------------------------------------------
// GCNEncoder: 3 stacked GCNConv layers (symmetric norm, self-loops) + ReLU.
//   R10: transforms re-tiled to fix the LDS:FMA pipe ratio. R9 analysis:
//       4 waves share one LDS pipe -> old shape (8 reads : 64 FMA) was 3x
//       LDS-oversubscribed (41us = pure ds_read time). New shape: 1-wave
//       blocks, TM=8 x TN=8 (16 reads : 256 FMA per k4), TILE_M=64(t1)/
//       128(t2), 40KB LDS -> 4 blocks/CU (1 wave/SIMD); staging overlaps
//       across independent blocks. XOR swizzle keeps X reads conflict-free
//       (8 distinct rows per ds_read_b128 spread over 8 bank groups).
//   Carried: XCD-partitioned hist/fill, edge-group-parallel aggregates,
//   fused W3, merged init/detect + scan3, custom zero.
// ---------------------------------------------------------------------------

#define FULL_GRID 2048
#define PARTS 8

typedef const __attribute__((address_space(1))) void* gas_ptr;
typedef __attribute__((address_space(3))) void* las_ptr;

__device__ __forceinline__ void gld16(const void* g, void* l) {
  __builtin_amdgcn_global_load_lds((gas_ptr)g, (las_ptr)l, 16, 0, 0);
}

// blocks 0..n-1: zero counts; last block: edge dtype detect.
__global__ __launch_bounds__(256) void k_init(int* __restrict__ p, int n4,
                                              const unsigned int* __restrict__ words,
                                              int* __restrict__ flag) {
  if (blockIdx.x == gridDim.x - 1) {
    __shared__ int sm[256];
    int cnt = 0;
    #pragma unroll
    for (int j = 0; j < 8; ++j) {
      int idx = (threadIdx.x * 8 + j) * 2 + 1;  // odd words of first 4096 words
      cnt += (words[idx] == 0u) ? 1 : 0;
    }
    sm[threadIdx.x] = cnt;
    __syncthreads();
    for (int off = 128; off > 0; off >>= 1) {
      if (threadIdx.x < off) sm[threadIdx.x] += sm[threadIdx.x + off];
      __syncthreads();
    }
    if (threadIdx.x == 0) flag[0] = (sm[0] > 1024) ? 1 : 0;
    return;
  }
  int i = blockIdx.x * blockDim.x + threadIdx.x;
  const int stride = (gridDim.x - 1) * blockDim.x;
  int4* p4 = (int4*)p;
  for (; i < n4; i += stride) p4[i] = make_int4(0, 0, 0, 0);
}

// XCD-partitioned histogram: partition p = blockIdx&7 handles dst range
// [lo,hi) so atomics on counts stay in one XCD's L2.
__global__ __launch_bounds__(256) void k_hist(const void* __restrict__ eraw, int E,
                                              int N, const int* __restrict__ flag,
                                              int* __restrict__ counts) {
  const int is64 = flag[0];
  const int part = blockIdx.x & (PARTS - 1);
  const int lo = (int)((long long)N * part / PARTS);
  const int hi = (int)((long long)N * (part + 1) / PARTS);
  int i = (blockIdx.x >> 3) * blockDim.x + threadIdx.x;
  const int stride = (gridDim.x >> 3) * blockDim.x;
  if (is64) {
    const long long* e = (const long long*)eraw;
    for (; i < E; i += stride) {
      const int d = (int)e[(long long)E + i];
      if (d >= lo && d < hi) atomicAdd(&counts[d], 1);
    }
  } else {
    const int* e = (const int*)eraw;
    for (; i < E; i += stride) {
      const int d = e[E + i];
      if (d >= lo && d < hi) atomicAdd(&counts[d], 1);
    }
  }
}

__global__ __launch_bounds__(1024) void k_scan1(const int* __restrict__ counts,
                                                int* __restrict__ scanned,
                                                int* __restrict__ partials, int n) {
  __shared__ int sm[1024];
  const int i = blockIdx.x * 1024 + threadIdx.x;
  const int v = (i < n) ? counts[i] : 0;
  sm[threadIdx.x] = v;
  __syncthreads();
  for (int off = 1; off < 1024; off <<= 1) {
    int t = sm[threadIdx.x];
    int u = (threadIdx.x >= off) ? sm[threadIdx.x - off] : 0;
    __syncthreads();
    sm[threadIdx.x] = t + u;
    __syncthreads();
  }
  const int inc = sm[threadIdx.x];
  if (i < n) scanned[i] = inc - v;  // exclusive within block
  if (threadIdx.x == 1023) partials[blockIdx.x] = inc;  // block total
}

// scan of partials folded in: each block scans partials[] in LDS (NB <= 1024).
__global__ __launch_bounds__(256) void k_scan3(const int* __restrict__ scanned,
                                               const int* __restrict__ partials,
                                               int nb,
                                               const int* __restrict__ counts,
                                               int* __restrict__ offsets,
                                               int* __restrict__ cursor,
                                               float* __restrict__ dinv, int n) {
  __shared__ int ps[1024];
  for (int t = threadIdx.x; t < nb; t += 256) ps[t] = partials[t];
  __syncthreads();
  if (threadIdx.x == 0) {  // serial exclusive scan of <=1024 block totals
    int run = 0;
    for (int b = 0; b < nb; ++b) { const int v = ps[b]; ps[b] = run; run += v; }
  }
  __syncthreads();
  int i = blockIdx.x * blockDim.x + threadIdx.x;
  const int stride = gridDim.x * blockDim.x;
  for (; i < n; i += stride) {
    const int o = scanned[i] + ps[i >> 10];
    offsets[i] = o;
    cursor[i] = o;
    dinv[i] = rsqrtf((float)counts[i] + 1.0f);  // +1 self-loop
  }
}

// XCD-partitioned fill: stores to elist confined to this partition's slice.
__global__ __launch_bounds__(256) void k_fill(const void* __restrict__ eraw, int E,
                                              int N, const int* __restrict__ flag,
                                              int* __restrict__ cursor,
                                              int* __restrict__ elist) {
  const int is64 = flag[0];
  const int part = blockIdx.x & (PARTS - 1);
  const int lo = (int)((long long)N * part / PARTS);
  const int hi = (int)((long long)N * (part + 1) / PARTS);
  int i = (blockIdx.x >> 3) * blockDim.x + threadIdx.x;
  const int stride = (gridDim.x >> 3) * blockDim.x;
  if (is64) {
    const long long* e = (const long long*)eraw;
    for (; i < E; i += stride) {
      const int d = (int)e[(long long)E + i];
      if (d >= lo && d < hi) {
        const int s = (int)e[i];
        elist[atomicAdd(&cursor[d], 1)] = s;
      }
    }
  } else {
    const int* e = (const int*)eraw;
    for (; i < E; i += stride) {
      const int d = e[E + i];
      if (d >= lo && d < hi) {
        const int s = e[i];
        elist[atomicAdd(&cursor[d], 1)] = s;
      }
    }
  }
}

__device__ __forceinline__ float f4get(const float4& v, int j) {
  return j == 0 ? v.x : (j == 1 ? v.y : (j == 2 ? v.z : v.w));
}

// hs = dinv .* (X @ W). ONE-WAVE blocks, TM=8 x TN=8 thread tile.
// COLT = F_OUT/8 col-threads, ROWT = 64/COLT row-threads, TILE_M = 8*ROWT.
// Per k4-step: 8 W + 8 X ds_read_b128 feed 256 FMA-instr (16:256 ratio).
// X tile XOR-swizzled (pre-swizzled global_load_lds source, swizzled read).
// W in KC-chunks, double-buffered. LDS ~40KB -> 4 blocks/CU (1 wave/SIMD).
template <int F_IN, int F_OUT, int KC>
__global__ __launch_bounds__(64) void k_transform(const float* __restrict__ X,
                                                  const float* __restrict__ W,
                                                  const float* __restrict__ dinv,
                                                  float* __restrict__ H, int n) {
  constexpr int COLT = F_OUT / 8;       // col-thread groups (8 cols each)
  constexpr int ROWT = 64 / COLT;       // row-threads
  constexpr int TILE_M = 8 * ROWT;      // rows per block (TM=8)
  constexpr int K4 = F_IN / 4;
  constexpr int NKC = F_IN / KC;
  constexpr int NWB = (NKC > 1) ? 2 : 1;
  constexpr int F4 = F_OUT / 4;
  static_assert(COLT * 8 == F_OUT && ROWT * COLT == 64, "tiling");
  static_assert(K4 >= 8 && (ROWT % 8) == 0, "swizzle");
  static_assert((TILE_M * F_IN * 4) % 1024 == 0, "X segs");
  static_assert((KC * F_OUT * 4) % 1024 == 0, "W segs");

  __shared__ __align__(16) float Xs[TILE_M * F_IN];
  __shared__ __align__(16) float Ws[NWB][KC * F_OUT];

  const int lane = threadIdx.x;
  const long long base = (long long)blockIdx.x * TILE_M;
  const float4* __restrict__ X4 = (const float4*)X;

  // ---- stage X tile (pre-swizzled source -> linear LDS dest) ----
  constexpr int XSEG = TILE_M * F_IN * 4 / 1024;
  if (base + TILE_M <= n) {
    #pragma unroll
    for (int j = 0; j < XSEG; ++j) {
      const int slot = j * 64 + lane;       // linear float4 slot
      const int row = slot / K4;
      const int c = slot % K4;
      gld16(&X4[(base + row) * K4 + (c ^ (row & 7))], &Xs[j * 256]);
    }
  } else {
    for (int slot = lane; slot < TILE_M * K4; slot += 64) {
      const int row = slot / K4;
      const int c = slot % K4;
      float4 v = make_float4(0.f, 0.f, 0.f, 0.f);
      if (base + row < n) v = X4[(base + row) * K4 + (c ^ (row & 7))];
      ((float4*)Xs)[slot] = v;
    }
  }

  // ---- stage W chunk 0 ----
  constexpr int WSEG = KC * F_OUT * 4 / 1024;
  #pragma unroll
  for (int j = 0; j < WSEG; ++j) gld16(W + j * 256 + lane * 4, &Ws[0][j * 256]);

  const int ct = lane % COLT;
  const int rt = lane / COLT;
  const int sw = rt & 7;  // row&7 invariant across r (r*ROWT ≡ 0 mod 8)

  float4 acc[8][2];
  #pragma unroll
  for (int r = 0; r < 8; ++r) {
    acc[r][0] = make_float4(0.f, 0.f, 0.f, 0.f);
    acc[r][1] = make_float4(0.f, 0.f, 0.f, 0.f);
  }

  const float4* Xs4 = (const float4*)Xs;

  for (int kc = 0; kc < NKC; ++kc) {
    __syncthreads();  // staged data visible (barrier drains vmcnt)
    if (NKC > 1 && kc + 1 < NKC) {  // prefetch next W chunk
      const float* wb = W + (kc + 1) * KC * F_OUT;
      #pragma unroll
      for (int j = 0; j < WSEG; ++j)
        gld16(wb + j * 256 + lane * 4, &Ws[(kc + 1) & (NWB - 1)][j * 256]);
    }
    const float4* Ws4 = (const float4*)Ws[kc & (NWB - 1)];
    #pragma unroll
    for (int lk4 = 0; lk4 < KC / 4; ++lk4) {
      const int kk = kc * (KC / 4) + lk4;   // global k4 index
      float4 wv[4][2];
      #pragma unroll
      for (int j = 0; j < 4; ++j) {         // 8 cols x 1 k per pair
        wv[j][0] = Ws4[(lk4 * 4 + j) * F4 + 2 * ct + 0];
        wv[j][1] = Ws4[(lk4 * 4 + j) * F4 + 2 * ct + 1];
      }
      #pragma unroll
      for (int r = 0; r < 8; ++r) {
        const float4 xv = Xs4[(rt + r * ROWT) * K4 + (kk ^ sw)];
        #pragma unroll
        for (int j = 0; j < 4; ++j) {
          const float xs = f4get(xv, j);
          acc[r][0].x = fmaf(xs, wv[j][0].x, acc[r][0].x);
          acc[r][0].y = fmaf(xs, wv[j][0].y, acc[r][0].y);
          acc[r][0].z = fmaf(xs, wv[j][0].z, acc[r][0].z);
          acc[r][0].w = fmaf(xs, wv[j][0].w, acc[r][0].w);
          acc[r][1].x = fmaf(xs, wv[j][1].x, acc[r][1].x);
          acc[r][1].y = fmaf(xs, wv[j][1].y, acc[r][1].y);
          acc[r][1].z = fmaf(xs, wv[j][1].z, acc[r][1].z);
          acc[r][1].w = fmaf(xs, wv[j][1].w, acc[r][1].w);
        }
      }
    }
  }

  #pragma unroll
  for (int r = 0; r < 8; ++r) {
    const long long row = base + rt + r * ROWT;
    if (row < n) {
      const float di = dinv[row];
      #pragma unroll
      for (int c4 = 0; c4 < 2; ++c4) {
        float4 v = acc[r][c4];
        v.x *= di; v.y *= di; v.z *= di; v.w *= di;
        *(float4*)&H[row * F_OUT + ct * 8 + c4 * 4] = v;
      }
    }
  }
}

// Edge-group-parallel aggregate. Wave = one dst node; LPE=F/4 lanes per edge
// (float4 feature slice), EPW=64/LPE edges per wave-instruction, 2 batches in
// flight. Cross-edge-group reduce via shfl_xor.
// out[d][:] = relu?(b + dinv[d]*(hs[d] + sum_s hs[s]))
// FUSE_W3: instead writes hs3 = dinv .* (relu(out2) @ W3)  (2 floats).
template <int F, bool RELU_OUT, bool FUSE_W3>
__global__ __launch_bounds__(256) void k_agg_vec(const float* __restrict__ HS,
                                                 const float* __restrict__ dinv,
                                                 const int* __restrict__ offsets,
                                                 const int* __restrict__ counts,
                                                 const int* __restrict__ elist,
                                                 const float* __restrict__ bias,
                                                 const float* __restrict__ W3,
                                                 float* __restrict__ out, int n) {
  constexpr int LPE = F / 4;        // lanes per edge
  constexpr int EPW = 64 / LPE;     // edges per wave-instruction
  const int lane = threadIdx.x & 63;
  const int wv = (blockIdx.x * (blockDim.x >> 6)) + (threadIdx.x >> 6);
  const int nwaves = gridDim.x * (blockDim.x >> 6);
  const int g = lane / LPE;         // edge slot within batch
  const int fl = lane % LPE;        // feature-slice index
  const float4 bf = *(const float4*)&bias[fl * 4];

  float w3a0 = 0.f, w3a1 = 0.f, w3a2 = 0.f, w3a3 = 0.f;
  float w3b0 = 0.f, w3b1 = 0.f, w3b2 = 0.f, w3b3 = 0.f;
  if (FUSE_W3) {
    w3a0 = W3[(fl * 4 + 0) * 2 + 0]; w3b0 = W3[(fl * 4 + 0) * 2 + 1];
    w3a1 = W3[(fl * 4 + 1) * 2 + 0]; w3b1 = W3[(fl * 4 + 1) * 2 + 1];
    w3a2 = W3[(fl * 4 + 2) * 2 + 0]; w3b2 = W3[(fl * 4 + 2) * 2 + 1];
    w3a3 = W3[(fl * 4 + 3) * 2 + 0]; w3b3 = W3[(fl * 4 + 3) * 2 + 1];
  }

  for (long long d = wv; d < n; d += nwaves) {
    const float di = dinv[d];
    const int start = offsets[d];
    const int cnt = counts[d];
    float4 acc = make_float4(0.f, 0.f, 0.f, 0.f);
    if (g == 0) acc = *(const float4*)&HS[d * F + fl * 4];  // self (pre-scaled)

    for (int j = 0; j < cnt; j += 2 * EPW) {
      const int e0 = j + g;
      const int e1 = j + EPW + g;
      const int i0 = elist[start + (e0 < cnt ? e0 : cnt - 1)];
      const int i1 = elist[start + (e1 < cnt ? e1 : cnt - 1)];
      const float4 v0 = *(const float4*)&HS[(long long)i0 * F + fl * 4];
      const float4 v1 = *(const float4*)&HS[(long long)i1 * F + fl * 4];
      if (e0 < cnt) {
        acc.x += v0.x; acc.y += v0.y; acc.z += v0.z; acc.w += v0.w;
      }
      if (e1 < cnt) {
        acc.x += v1.x; acc.y += v1.y; acc.z += v1.z; acc.w += v1.w;
      }
    }
    // reduce across edge groups (lanes differing in bits >= log2(LPE))
    #pragma unroll
    for (int m = LPE; m < 64; m <<= 1) {
      acc.x += __shfl_xor(acc.x, m, 64);
      acc.y += __shfl_xor(acc.y, m, 64);
      acc.z += __shfl_xor(acc.z, m, 64);
      acc.w += __shfl_xor(acc.w, m, 64);
    }
    float4 r;
    r.x = fmaf(di, acc.x, bf.x);
    r.y = fmaf(di, acc.y, bf.y);
    r.z = fmaf(di, acc.z, bf.z);
    r.w = fmaf(di, acc.w, bf.w);
    if (RELU_OUT) {
      r.x = fmaxf(r.x, 0.f); r.y = fmaxf(r.y, 0.f);
      r.z = fmaxf(r.z, 0.f); r.w = fmaxf(r.w, 0.f);
    }
    if (!FUSE_W3) {
      if (g == 0) *(float4*)&out[d * F + fl * 4] = r;
    } else {
      float t0 = r.x * w3a0 + r.y * w3a1 + r.z * w3a2 + r.w * w3a3;
      float t1 = r.x * w3b0 + r.y * w3b1 + r.z * w3b2 + r.w * w3b3;
      #pragma unroll
      for (int m = 1; m < LPE; m <<= 1) {
        t0 += __shfl_xor(t0, m, 64);
        t1 += __shfl_xor(t1, m, 64);
      }
      if (lane == 0) {
        out[d * 2 + 0] = di * t0;
        out[d * 2 + 1] = di * t1;
      }
    }
  }
}

// scalar aggregate for tiny F (layer 3, F=2)
template <int F, bool RELU_OUT>
__global__ __launch_bounds__(256) void k_aggregate(const float* __restrict__ HS,
                                                   const float* __restrict__ dinv,
                                                   const int* __restrict__ offsets,
                                                   const int* __restrict__ counts,
                                                   const int* __restrict__ elist,
                                                   const float* __restrict__ bias,
                                                   float* __restrict__ out, int n) {
  const int f = threadIdx.x % F;
  const int grp = threadIdx.x / F;
  constexpr int GRPS = 256 / F;
  const float bf = bias[f];

  for (long long d = (long long)blockIdx.x * GRPS + grp; d < n;
       d += (long long)gridDim.x * GRPS) {
    const float di = dinv[d];
    float acc = HS[d * F + f];  // self-loop (already dinv[d]-scaled)
    const int start = offsets[d];
    const int cnt = counts[d];
    for (int j = 0; j < cnt; j += 8) {
      int idx[8];
      float v[8];
      #pragma unroll
      for (int t = 0; t < 8; ++t) {
        const int jj = (j + t < cnt) ? (j + t) : j;
        idx[t] = elist[start + jj];
      }
      #pragma unroll
      for (int t = 0; t < 8; ++t) v[t] = HS[(long long)idx[t] * F + f];
      #pragma unroll
      for (int t = 0; t < 8; ++t) acc += (j + t < cnt) ? v[t] : 0.f;
    }
    float r = fmaf(di, acc, bf);
    if (RELU_OUT) r = fmaxf(r, 0.f);
    out[d * F + f] = r;
  }
}

extern "C" void kernel_launch(void* const* d_in, const int* in_sizes, int n_in,
                              void* d_out, int out_size, void* d_ws, size_t ws_size,
                              hipStream_t stream) {
  const float* x = (const float*)d_in[0];
  const void* eraw = d_in[1];
  const float* W1 = (const float*)d_in[2];
  const float* b1 = (const float*)d_in[3];
  const float* W2 = (const float*)d_in[4];
  const float* b2 = (const float*)d_in[5];
  const float* W3 = (const float*)d_in[6];
  const float* b3 = (const float*)d_in[7];
  float* out = (float*)d_out;

  const int N = in_sizes[0] / 128;  // 100000
  const int E = in_sizes[1] / 2;    // 600000

  char* ws = (char*)d_ws;
  size_t off = 0;
  auto alloc = [&](size_t bytes) -> char* {
    char* p = ws + off;
    off = (off + bytes + 255) & ~(size_t)255;
    return p;
  };
  int*   flag     = (int*)alloc(256);
  int*   counts   = (int*)alloc((size_t)N * 4 + 16);
  int*   scanned  = (int*)alloc((size_t)N * 4);
  int*   partials = (int*)alloc(1024 * 4);
  int*   offsets  = (int*)alloc((size_t)N * 4);
  int*   cursor   = (int*)alloc((size_t)N * 4);
  int*   elist    = (int*)alloc((size_t)E * 4);
  float* dinv     = (float*)alloc((size_t)N * 4);
  float* hbuf     = (float*)alloc((size_t)N * 64 * 4);  // hs1 [N,64]; later hs3 [N,2]
  float* obuf     = (float*)alloc((size_t)N * 64 * 4);  // out1 [N,64]
  float* h2buf    = (float*)alloc((size_t)N * 32 * 4);  // hs2 [N,32]
  (void)ws_size; (void)n_in; (void)out_size;

  // ---- CSR build ----
  k_init<<<129, 256, 0, stream>>>(counts, (N + 3) / 4, (const unsigned int*)eraw,
                                  flag);
  k_hist<<<FULL_GRID, 256, 0, stream>>>(eraw, E, N, flag, counts);
  const int NB = (N + 1023) >> 10;
  k_scan1<<<NB, 1024, 0, stream>>>(counts, scanned, partials, N);
  k_scan3<<<(N + 255) / 256, 256, 0, stream>>>(scanned, partials, NB, counts,
                                               offsets, cursor, dinv, N);
  k_fill<<<FULL_GRID, 256, 0, stream>>>(eraw, E, N, flag, cursor, elist);

  // ---- layer 1: hs1 = dinv.*(x@W1); out1 = relu(agg(hs1)) ----
  k_transform<128, 64, 16><<<(N + 63) / 64, 64, 0, stream>>>(x, W1, dinv, hbuf, N);
  k_agg_vec<64, true, false><<<FULL_GRID, 256, 0, stream>>>(
      hbuf, dinv, offsets, counts, elist, b1, nullptr, obuf, N);

  // ---- layer 2: hs2 = dinv.*(out1@W2); agg + ReLU + fused W3 -> hs3 ----
  k_transform<64, 32, 16><<<(N + 127) / 128, 64, 0, stream>>>(obuf, W2, dinv,
                                                              h2buf, N);
  k_agg_vec<32, true, true><<<FULL_GRID, 256, 0, stream>>>(
      h2buf, dinv, offsets, counts, elist, b2, W3, hbuf, N);

  // ---- layer 3: agg hs3 + ReLU -> out ----
  k_aggregate<2, true><<<(N + 127) / 128, 256, 0, stream>>>(
      hbuf, dinv, offsets, counts, elist, b3, out, N);
}

// Round 11
// 172.277 us; speedup vs baseline: 1.1422x; 1.1422x over previous
//
#include <hip/hip_runtime.h>
#include <math.h>

// ---------------------------------------------------------------------------
// GCNEncoder: 3 stacked GCNConv layers (symmetric norm, self-loops) + ReLU.
//   R11: transforms moved to MATRIX CORES via 3-term bf16 split
//       (h = xh@Wh + xh@Wl + xl@Wh; err ~1e-4 vs 6e-3 threshold).
//       R5..R10 showed the fp32 VALU GEMM is LDS-pipe-bound at ~41us; MFMA
//       cuts LDS traffic ~400x. W pre-packed once into B-fragment order
//       (k_prepw); X converted fp32->(hi,lo) bf16 during LDS staging.
//       mfma_f32_16x16x32_bf16 layouts: A row=lane&15,k=8*(lane>>4)+e;
//       B col=lane&15 same k; D col=lane&15,row=(lane>>4)*4+reg (m89).
//   Carried (R9 config): XCD-partitioned hist/fill, edge-group-parallel
//   aggregates, fused W3, merged init/detect + scan3.
// ---------------------------------------------------------------------------

#define FULL_GRID 2048
#define PARTS 8

typedef const __attribute__((address_space(1))) void* gas_ptr;
typedef __attribute__((address_space(3))) void* las_ptr;
typedef __attribute__((ext_vector_type(8))) short bf16x8;
typedef __attribute__((ext_vector_type(4))) float f32x4;

__device__ __forceinline__ void gld16(const void* g, void* l) {
  __builtin_amdgcn_global_load_lds((gas_ptr)g, (las_ptr)l, 16, 0, 0);
}

__device__ __forceinline__ unsigned short f2bf(float f) {  // RNE fp32->bf16
  unsigned int u = __float_as_uint(f);
  u += 0x7FFF + ((u >> 16) & 1);
  return (unsigned short)(u >> 16);
}
__device__ __forceinline__ float bf2f(unsigned short h) {
  return __uint_as_float(((unsigned int)h) << 16);
}

// blocks 0..n-1: zero counts; last block: edge dtype detect.
__global__ __launch_bounds__(256) void k_init(int* __restrict__ p, int n4,
                                              const unsigned int* __restrict__ words,
                                              int* __restrict__ flag) {
  if (blockIdx.x == gridDim.x - 1) {
    __shared__ int sm[256];
    int cnt = 0;
    #pragma unroll
    for (int j = 0; j < 8; ++j) {
      int idx = (threadIdx.x * 8 + j) * 2 + 1;  // odd words of first 4096 words
      cnt += (words[idx] == 0u) ? 1 : 0;
    }
    sm[threadIdx.x] = cnt;
    __syncthreads();
    for (int off = 128; off > 0; off >>= 1) {
      if (threadIdx.x < off) sm[threadIdx.x] += sm[threadIdx.x + off];
      __syncthreads();
    }
    if (threadIdx.x == 0) flag[0] = (sm[0] > 1024) ? 1 : 0;
    return;
  }
  int i = blockIdx.x * blockDim.x + threadIdx.x;
  const int stride = (gridDim.x - 1) * blockDim.x;
  int4* p4 = (int4*)p;
  for (; i < n4; i += stride) p4[i] = make_int4(0, 0, 0, 0);
}

// Pack W1 (128x64) and W2 (64x32) into MFMA B-fragment order, hi+lo bf16.
// frag elem p = ((kt*NT + nt)*64 + lane)*8 + e ; k = kt*32+8*(lane>>4)+e ;
// n = nt*16 + (lane&15).
__global__ __launch_bounds__(256) void k_prepw(const float* __restrict__ W1,
                                               const float* __restrict__ W2,
                                               short* __restrict__ Wh1,
                                               short* __restrict__ Wl1,
                                               short* __restrict__ Wh2,
                                               short* __restrict__ Wl2) {
  const int t = blockIdx.x * 256 + threadIdx.x;
  const int stride = gridDim.x * 256;
  for (int p = t; p < 4 * 4 * 64 * 8; p += stride) {  // W1: KT=4, NT=4
    const int e = p & 7, lane = (p >> 3) & 63, nt = (p >> 9) & 3, kt = p >> 11;
    const int k = kt * 32 + (lane >> 4) * 8 + e;
    const int nn = nt * 16 + (lane & 15);
    const float f = W1[k * 64 + nn];
    const unsigned short h = f2bf(f);
    Wh1[p] = (short)h;
    Wl1[p] = (short)f2bf(f - bf2f(h));
  }
  for (int p = t; p < 2 * 2 * 64 * 8; p += stride) {  // W2: KT=2, NT=2
    const int e = p & 7, lane = (p >> 3) & 63, nt = (p >> 9) & 1, kt = p >> 10;
    const int k = kt * 32 + (lane >> 4) * 8 + e;
    const int nn = nt * 16 + (lane & 15);
    const float f = W2[k * 32 + nn];
    const unsigned short h = f2bf(f);
    Wh2[p] = (short)h;
    Wl2[p] = (short)f2bf(f - bf2f(h));
  }
}

// XCD-partitioned histogram.
__global__ __launch_bounds__(256) void k_hist(const void* __restrict__ eraw, int E,
                                              int N, const int* __restrict__ flag,
                                              int* __restrict__ counts) {
  const int is64 = flag[0];
  const int part = blockIdx.x & (PARTS - 1);
  const int lo = (int)((long long)N * part / PARTS);
  const int hi = (int)((long long)N * (part + 1) / PARTS);
  int i = (blockIdx.x >> 3) * blockDim.x + threadIdx.x;
  const int stride = (gridDim.x >> 3) * blockDim.x;
  if (is64) {
    const long long* e = (const long long*)eraw;
    for (; i < E; i += stride) {
      const int d = (int)e[(long long)E + i];
      if (d >= lo && d < hi) atomicAdd(&counts[d], 1);
    }
  } else {
    const int* e = (const int*)eraw;
    for (; i < E; i += stride) {
      const int d = e[E + i];
      if (d >= lo && d < hi) atomicAdd(&counts[d], 1);
    }
  }
}

__global__ __launch_bounds__(1024) void k_scan1(const int* __restrict__ counts,
                                                int* __restrict__ scanned,
                                                int* __restrict__ partials, int n) {
  __shared__ int sm[1024];
  const int i = blockIdx.x * 1024 + threadIdx.x;
  const int v = (i < n) ? counts[i] : 0;
  sm[threadIdx.x] = v;
  __syncthreads();
  for (int off = 1; off < 1024; off <<= 1) {
    int t = sm[threadIdx.x];
    int u = (threadIdx.x >= off) ? sm[threadIdx.x - off] : 0;
    __syncthreads();
    sm[threadIdx.x] = t + u;
    __syncthreads();
  }
  const int inc = sm[threadIdx.x];
  if (i < n) scanned[i] = inc - v;  // exclusive within block
  if (threadIdx.x == 1023) partials[blockIdx.x] = inc;  // block total
}

__global__ __launch_bounds__(256) void k_scan3(const int* __restrict__ scanned,
                                               const int* __restrict__ partials,
                                               int nb,
                                               const int* __restrict__ counts,
                                               int* __restrict__ offsets,
                                               int* __restrict__ cursor,
                                               float* __restrict__ dinv, int n) {
  __shared__ int ps[1024];
  for (int t = threadIdx.x; t < nb; t += 256) ps[t] = partials[t];
  __syncthreads();
  if (threadIdx.x == 0) {
    int run = 0;
    for (int b = 0; b < nb; ++b) { const int v = ps[b]; ps[b] = run; run += v; }
  }
  __syncthreads();
  int i = blockIdx.x * blockDim.x + threadIdx.x;
  const int stride = gridDim.x * blockDim.x;
  for (; i < n; i += stride) {
    const int o = scanned[i] + ps[i >> 10];
    offsets[i] = o;
    cursor[i] = o;
    dinv[i] = rsqrtf((float)counts[i] + 1.0f);  // +1 self-loop
  }
}

// XCD-partitioned fill.
__global__ __launch_bounds__(256) void k_fill(const void* __restrict__ eraw, int E,
                                              int N, const int* __restrict__ flag,
                                              int* __restrict__ cursor,
                                              int* __restrict__ elist) {
  const int is64 = flag[0];
  const int part = blockIdx.x & (PARTS - 1);
  const int lo = (int)((long long)N * part / PARTS);
  const int hi = (int)((long long)N * (part + 1) / PARTS);
  int i = (blockIdx.x >> 3) * blockDim.x + threadIdx.x;
  const int stride = (gridDim.x >> 3) * blockDim.x;
  if (is64) {
    const long long* e = (const long long*)eraw;
    for (; i < E; i += stride) {
      const int d = (int)e[(long long)E + i];
      if (d >= lo && d < hi) {
        const int s = (int)e[i];
        elist[atomicAdd(&cursor[d], 1)] = s;
      }
    }
  } else {
    const int* e = (const int*)eraw;
    for (; i < E; i += stride) {
      const int d = e[E + i];
      if (d >= lo && d < hi) {
        const int s = e[i];
        elist[atomicAdd(&cursor[d], 1)] = s;
      }
    }
  }
}

// hs = dinv .* (X @ W) via bf16-split MFMA. Block = 256 thr / 4 waves,
// tile = 64 rows; wave w computes rows [w*16, w*16+16) x all F_OUT cols.
// X staged fp32->(hi,lo) bf16 in XOR-swizzled 16B slots; W frags pre-packed.
template <int F_IN, int F_OUT>
__global__ __launch_bounds__(256) void k_transform_mfma(
    const float* __restrict__ X, const short* __restrict__ Wh,
    const short* __restrict__ Wl, const float* __restrict__ dinv,
    float* __restrict__ H, int n) {
  constexpr int KT = F_IN / 32;
  constexpr int NT = F_OUT / 16;
  constexpr int K4f = F_IN / 4;        // float4 per row
  constexpr int SLOTS = F_IN / 8;      // 16B bf16 slots per row
  constexpr int TILE_M = 64;
  constexpr int WFRAG = KT * NT * 64 * 8;  // shorts per W array
  static_assert((WFRAG * 2) % 1024 == 0, "W segs");

  __shared__ __align__(16) unsigned short Xh[TILE_M * F_IN];
  __shared__ __align__(16) unsigned short Xl[TILE_M * F_IN];
  __shared__ __align__(16) unsigned short Whs[WFRAG];
  __shared__ __align__(16) unsigned short Wls[WFRAG];

  const int tid = threadIdx.x;
  const int lane = tid & 63;
  const int wid = tid >> 6;
  const long long base = (long long)blockIdx.x * TILE_M;

  // ---- stage packed W fragments (async DMA, linear dest) ----
  constexpr int WSEGS = WFRAG * 2 / 1024;
  for (int seg = wid; seg < WSEGS; seg += 4) {
    gld16((const char*)Wh + seg * 1024 + lane * 16, (char*)Whs + seg * 1024);
    gld16((const char*)Wl + seg * 1024 + lane * 16, (char*)Wls + seg * 1024);
  }

  // ---- stage X tile: fp32 -> hi/lo bf16, swizzled slot = (c4>>1)^(row&mask) ----
  const float4* __restrict__ X4 = (const float4*)X;
  for (int g = tid; g < TILE_M * K4f; g += 256) {
    const int row = g / K4f, c4 = g % K4f;
    float4 v = make_float4(0.f, 0.f, 0.f, 0.f);
    if (base + row < n) v = X4[(base + row) * K4f + c4];
    ushort4 hv, lv;
    hv.x = f2bf(v.x); lv.x = f2bf(v.x - bf2f(hv.x));
    hv.y = f2bf(v.y); lv.y = f2bf(v.y - bf2f(hv.y));
    hv.z = f2bf(v.z); lv.z = f2bf(v.z - bf2f(hv.z));
    hv.w = f2bf(v.w); lv.w = f2bf(v.w - bf2f(hv.w));
    const int slot = (c4 >> 1) ^ (row & (SLOTS - 1));
    const int boff = row * (F_IN * 2) + slot * 16 + (c4 & 1) * 8;
    *(ushort4*)((char*)Xh + boff) = hv;
    *(ushort4*)((char*)Xl + boff) = lv;
  }
  __syncthreads();  // barrier drains gld16 vmcnt + lds writes

  // ---- MFMA compute ----
  const int arow = lane & 15;   // A row within stripe / D col
  const int kg = lane >> 4;     // k-group
  const int lrow = wid * 16 + arow;

  f32x4 acc[NT];
  #pragma unroll
  for (int t = 0; t < NT; ++t) {
    f32x4 z = {0.f, 0.f, 0.f, 0.f};
    acc[t] = z;
  }

  #pragma unroll
  for (int kt = 0; kt < KT; ++kt) {
    const int slot = (kt * 4 + kg) ^ (lrow & (SLOTS - 1));
    const int aoff = lrow * (F_IN * 2) + slot * 16;
    const bf16x8 ah = *(const bf16x8*)((const char*)Xh + aoff);
    const bf16x8 al = *(const bf16x8*)((const char*)Xl + aoff);
    #pragma unroll
    for (int nt = 0; nt < NT; ++nt) {
      const int woff = ((kt * NT + nt) * 64 + lane) * 8;
      const bf16x8 bh = *(const bf16x8*)&Whs[woff];
      const bf16x8 bl = *(const bf16x8*)&Wls[woff];
      acc[nt] = __builtin_amdgcn_mfma_f32_16x16x32_bf16(ah, bh, acc[nt], 0, 0, 0);
      acc[nt] = __builtin_amdgcn_mfma_f32_16x16x32_bf16(ah, bl, acc[nt], 0, 0, 0);
      acc[nt] = __builtin_amdgcn_mfma_f32_16x16x32_bf16(al, bh, acc[nt], 0, 0, 0);
    }
  }

  // ---- epilogue: D row = (lane>>4)*4 + r, col = lane&15 ----
  #pragma unroll
  for (int r = 0; r < 4; ++r) {
    const long long row = base + wid * 16 + kg * 4 + r;
    if (row < n) {
      const float di = dinv[row];
      #pragma unroll
      for (int nt = 0; nt < NT; ++nt)
        H[row * F_OUT + nt * 16 + arow] = di * acc[nt][r];
    }
  }
}

// Edge-group-parallel aggregate (R9). Wave = one dst node; LPE=F/4 lanes/edge.
template <int F, bool RELU_OUT, bool FUSE_W3>
__global__ __launch_bounds__(256) void k_agg_vec(const float* __restrict__ HS,
                                                 const float* __restrict__ dinv,
                                                 const int* __restrict__ offsets,
                                                 const int* __restrict__ counts,
                                                 const int* __restrict__ elist,
                                                 const float* __restrict__ bias,
                                                 const float* __restrict__ W3,
                                                 float* __restrict__ out, int n) {
  constexpr int LPE = F / 4;
  constexpr int EPW = 64 / LPE;
  const int lane = threadIdx.x & 63;
  const int wv = (blockIdx.x * (blockDim.x >> 6)) + (threadIdx.x >> 6);
  const int nwaves = gridDim.x * (blockDim.x >> 6);
  const int g = lane / LPE;
  const int fl = lane % LPE;
  const float4 bf = *(const float4*)&bias[fl * 4];

  float w3a0 = 0.f, w3a1 = 0.f, w3a2 = 0.f, w3a3 = 0.f;
  float w3b0 = 0.f, w3b1 = 0.f, w3b2 = 0.f, w3b3 = 0.f;
  if (FUSE_W3) {
    w3a0 = W3[(fl * 4 + 0) * 2 + 0]; w3b0 = W3[(fl * 4 + 0) * 2 + 1];
    w3a1 = W3[(fl * 4 + 1) * 2 + 0]; w3b1 = W3[(fl * 4 + 1) * 2 + 1];
    w3a2 = W3[(fl * 4 + 2) * 2 + 0]; w3b2 = W3[(fl * 4 + 2) * 2 + 1];
    w3a3 = W3[(fl * 4 + 3) * 2 + 0]; w3b3 = W3[(fl * 4 + 3) * 2 + 1];
  }

  for (long long d = wv; d < n; d += nwaves) {
    const float di = dinv[d];
    const int start = offsets[d];
    const int cnt = counts[d];
    float4 acc = make_float4(0.f, 0.f, 0.f, 0.f);
    if (g == 0) acc = *(const float4*)&HS[d * F + fl * 4];  // self (pre-scaled)

    for (int j = 0; j < cnt; j += 2 * EPW) {
      const int e0 = j + g;
      const int e1 = j + EPW + g;
      const int i0 = elist[start + (e0 < cnt ? e0 : cnt - 1)];
      const int i1 = elist[start + (e1 < cnt ? e1 : cnt - 1)];
      const float4 v0 = *(const float4*)&HS[(long long)i0 * F + fl * 4];
      const float4 v1 = *(const float4*)&HS[(long long)i1 * F + fl * 4];
      if (e0 < cnt) {
        acc.x += v0.x; acc.y += v0.y; acc.z += v0.z; acc.w += v0.w;
      }
      if (e1 < cnt) {
        acc.x += v1.x; acc.y += v1.y; acc.z += v1.z; acc.w += v1.w;
      }
    }
    #pragma unroll
    for (int m = LPE; m < 64; m <<= 1) {
      acc.x += __shfl_xor(acc.x, m, 64);
      acc.y += __shfl_xor(acc.y, m, 64);
      acc.z += __shfl_xor(acc.z, m, 64);
      acc.w += __shfl_xor(acc.w, m, 64);
    }
    float4 r;
    r.x = fmaf(di, acc.x, bf.x);
    r.y = fmaf(di, acc.y, bf.y);
    r.z = fmaf(di, acc.z, bf.z);
    r.w = fmaf(di, acc.w, bf.w);
    if (RELU_OUT) {
      r.x = fmaxf(r.x, 0.f); r.y = fmaxf(r.y, 0.f);
      r.z = fmaxf(r.z, 0.f); r.w = fmaxf(r.w, 0.f);
    }
    if (!FUSE_W3) {
      if (g == 0) *(float4*)&out[d * F + fl * 4] = r;
    } else {
      float t0 = r.x * w3a0 + r.y * w3a1 + r.z * w3a2 + r.w * w3a3;
      float t1 = r.x * w3b0 + r.y * w3b1 + r.z * w3b2 + r.w * w3b3;
      #pragma unroll
      for (int m = 1; m < LPE; m <<= 1) {
        t0 += __shfl_xor(t0, m, 64);
        t1 += __shfl_xor(t1, m, 64);
      }
      if (lane == 0) {
        out[d * 2 + 0] = di * t0;
        out[d * 2 + 1] = di * t1;
      }
    }
  }
}

// scalar aggregate for tiny F (layer 3, F=2)
template <int F, bool RELU_OUT>
__global__ __launch_bounds__(256) void k_aggregate(const float* __restrict__ HS,
                                                   const float* __restrict__ dinv,
                                                   const int* __restrict__ offsets,
                                                   const int* __restrict__ counts,
                                                   const int* __restrict__ elist,
                                                   const float* __restrict__ bias,
                                                   float* __restrict__ out, int n) {
  const int f = threadIdx.x % F;
  const int grp = threadIdx.x / F;
  constexpr int GRPS = 256 / F;
  const float bf = bias[f];

  for (long long d = (long long)blockIdx.x * GRPS + grp; d < n;
       d += (long long)gridDim.x * GRPS) {
    const float di = dinv[d];
    float acc = HS[d * F + f];
    const int start = offsets[d];
    const int cnt = counts[d];
    for (int j = 0; j < cnt; j += 8) {
      int idx[8];
      float v[8];
      #pragma unroll
      for (int t = 0; t < 8; ++t) {
        const int jj = (j + t < cnt) ? (j + t) : j;
        idx[t] = elist[start + jj];
      }
      #pragma unroll
      for (int t = 0; t < 8; ++t) v[t] = HS[(long long)idx[t] * F + f];
      #pragma unroll
      for (int t = 0; t < 8; ++t) acc += (j + t < cnt) ? v[t] : 0.f;
    }
    float r = fmaf(di, acc, bf);
    if (RELU_OUT) r = fmaxf(r, 0.f);
    out[d * F + f] = r;
  }
}

extern "C" void kernel_launch(void* const* d_in, const int* in_sizes, int n_in,
                              void* d_out, int out_size, void* d_ws, size_t ws_size,
                              hipStream_t stream) {
  const float* x = (const float*)d_in[0];
  const void* eraw = d_in[1];
  const float* W1 = (const float*)d_in[2];
  const float* b1 = (const float*)d_in[3];
  const float* W2 = (const float*)d_in[4];
  const float* b2 = (const float*)d_in[5];
  const float* W3 = (const float*)d_in[6];
  const float* b3 = (const float*)d_in[7];
  float* out = (float*)d_out;

  const int N = in_sizes[0] / 128;  // 100000
  const int E = in_sizes[1] / 2;    // 600000

  char* ws = (char*)d_ws;
  size_t off = 0;
  auto alloc = [&](size_t bytes) -> char* {
    char* p = ws + off;
    off = (off + bytes + 255) & ~(size_t)255;
    return p;
  };
  int*   flag     = (int*)alloc(256);
  int*   counts   = (int*)alloc((size_t)N * 4 + 16);
  int*   scanned  = (int*)alloc((size_t)N * 4);
  int*   partials = (int*)alloc(1024 * 4);
  int*   offsets  = (int*)alloc((size_t)N * 4);
  int*   cursor   = (int*)alloc((size_t)N * 4);
  int*   elist    = (int*)alloc((size_t)E * 4);
  float* dinv     = (float*)alloc((size_t)N * 4);
  short* Wh1      = (short*)alloc(4 * 4 * 64 * 8 * 2);
  short* Wl1      = (short*)alloc(4 * 4 * 64 * 8 * 2);
  short* Wh2      = (short*)alloc(2 * 2 * 64 * 8 * 2);
  short* Wl2      = (short*)alloc(2 * 2 * 64 * 8 * 2);
  float* hbuf     = (float*)alloc((size_t)N * 64 * 4);  // hs1; later hs3 [N,2]
  float* obuf     = (float*)alloc((size_t)N * 64 * 4);  // out1 [N,64]
  float* h2buf    = (float*)alloc((size_t)N * 32 * 4);  // hs2 [N,32]
  (void)ws_size; (void)n_in; (void)out_size;

  // ---- CSR build + W pre-pack ----
  k_init<<<129, 256, 0, stream>>>(counts, (N + 3) / 4, (const unsigned int*)eraw,
                                  flag);
  k_prepw<<<32, 256, 0, stream>>>(W1, W2, Wh1, Wl1, Wh2, Wl2);
  k_hist<<<FULL_GRID, 256, 0, stream>>>(eraw, E, N, flag, counts);
  const int NB = (N + 1023) >> 10;
  k_scan1<<<NB, 1024, 0, stream>>>(counts, scanned, partials, N);
  k_scan3<<<(N + 255) / 256, 256, 0, stream>>>(scanned, partials, NB, counts,
                                               offsets, cursor, dinv, N);
  k_fill<<<FULL_GRID, 256, 0, stream>>>(eraw, E, N, flag, cursor, elist);

  // ---- layer 1: hs1 = dinv.*(x@W1); out1 = relu(agg(hs1)) ----
  k_transform_mfma<128, 64><<<(N + 63) / 64, 256, 0, stream>>>(
      x, Wh1, Wl1, dinv, hbuf, N);
  k_agg_vec<64, true, false><<<FULL_GRID, 256, 0, stream>>>(
      hbuf, dinv, offsets, counts, elist, b1, nullptr, obuf, N);

  // ---- layer 2: hs2 = dinv.*(out1@W2); agg + ReLU + fused W3 -> hs3 ----
  k_transform_mfma<64, 32><<<(N + 63) / 64, 256, 0, stream>>>(
      obuf, Wh2, Wl2, dinv, h2buf, N);
  k_agg_vec<32, true, true><<<FULL_GRID, 256, 0, stream>>>(
      h2buf, dinv, offsets, counts, elist, b2, W3, hbuf, N);

  // ---- layer 3: agg hs3 + ReLU -> out ----
  k_aggregate<2, true><<<(N + 127) / 128, 256, 0, stream>>>(
      hbuf, dinv, offsets, counts, elist, b3, out, N);
}

// Round 12
// 171.145 us; speedup vs baseline: 1.1497x; 1.0066x over previous
//
#include <hip/hip_runtime.h>
#include <math.h>

// ---------------------------------------------------------------------------
// GCNEncoder: 3 stacked GCNConv layers (symmetric norm, self-loops) + ReLU.
//   R12 (on R11's MFMA base):
//     (a) edges normalized to int32 once; XCD-partitioned hist/fill read
//         half the bytes across their 8 passes.
//     (b) aggregates process TWO nodes per wave (4 independent gathers in
//         flight) -- gather is latency-bound, not BW-bound.
//     (c) zero+detect+prepw merged into one k_init launch.
//   Carried: bf16-split MFMA transforms (h = xh@Wh + xh@Wl + xl@Wh),
//   XCD-partitioned hist/fill, fused W3, merged scan3.
// ---------------------------------------------------------------------------

#define FULL_GRID 2048
#define PARTS 8

typedef const __attribute__((address_space(1))) void* gas_ptr;
typedef __attribute__((address_space(3))) void* las_ptr;
typedef __attribute__((ext_vector_type(8))) short bf16x8;
typedef __attribute__((ext_vector_type(4))) float f32x4;

__device__ __forceinline__ void gld16(const void* g, void* l) {
  __builtin_amdgcn_global_load_lds((gas_ptr)g, (las_ptr)l, 16, 0, 0);
}

__device__ __forceinline__ unsigned short f2bf(float f) {  // RNE fp32->bf16
  unsigned int u = __float_as_uint(f);
  u += 0x7FFF + ((u >> 16) & 1);
  return (unsigned short)(u >> 16);
}
__device__ __forceinline__ float bf2f(unsigned short h) {
  return __uint_as_float(((unsigned int)h) << 16);
}

// blocks 0..127: zero counts; block 128: dtype detect; 129..160: prep W frags.
__global__ __launch_bounds__(256) void k_init(int* __restrict__ p, int n4,
                                              const unsigned int* __restrict__ words,
                                              int* __restrict__ flag,
                                              const float* __restrict__ W1,
                                              const float* __restrict__ W2,
                                              short* __restrict__ Wh1,
                                              short* __restrict__ Wl1,
                                              short* __restrict__ Wh2,
                                              short* __restrict__ Wl2) {
  if (blockIdx.x == 128) {  // dtype detect
    __shared__ int sm[256];
    int cnt = 0;
    #pragma unroll
    for (int j = 0; j < 8; ++j) {
      int idx = (threadIdx.x * 8 + j) * 2 + 1;  // odd words of first 4096 words
      cnt += (words[idx] == 0u) ? 1 : 0;
    }
    sm[threadIdx.x] = cnt;
    __syncthreads();
    for (int off = 128; off > 0; off >>= 1) {
      if (threadIdx.x < off) sm[threadIdx.x] += sm[threadIdx.x + off];
      __syncthreads();
    }
    if (threadIdx.x == 0) flag[0] = (sm[0] > 1024) ? 1 : 0;
    return;
  }
  if (blockIdx.x > 128) {  // W fragment prep
    const int t = (blockIdx.x - 129) * 256 + threadIdx.x;
    const int stride = 32 * 256;
    for (int q = t; q < 4 * 4 * 64 * 8; q += stride) {  // W1: KT=4, NT=4
      const int e = q & 7, lane = (q >> 3) & 63, nt = (q >> 9) & 3, kt = q >> 11;
      const int k = kt * 32 + (lane >> 4) * 8 + e;
      const int nn = nt * 16 + (lane & 15);
      const float f = W1[k * 64 + nn];
      const unsigned short h = f2bf(f);
      Wh1[q] = (short)h;
      Wl1[q] = (short)f2bf(f - bf2f(h));
    }
    for (int q = t; q < 2 * 2 * 64 * 8; q += stride) {  // W2: KT=2, NT=2
      const int e = q & 7, lane = (q >> 3) & 63, nt = (q >> 9) & 1, kt = q >> 10;
      const int k = kt * 32 + (lane >> 4) * 8 + e;
      const int nn = nt * 16 + (lane & 15);
      const float f = W2[k * 32 + nn];
      const unsigned short h = f2bf(f);
      Wh2[q] = (short)h;
      Wl2[q] = (short)f2bf(f - bf2f(h));
    }
    return;
  }
  int i = blockIdx.x * blockDim.x + threadIdx.x;  // zero counts
  const int stride = 128 * blockDim.x;
  int4* p4 = (int4*)p;
  for (; i < n4; i += stride) p4[i] = make_int4(0, 0, 0, 0);
}

// edge dtype normalize: int64|int32 -> int32 srcn/dstn (one pass).
__global__ __launch_bounds__(256) void k_normalize(const void* __restrict__ eraw,
                                                   int E,
                                                   const int* __restrict__ flag,
                                                   int* __restrict__ srcn,
                                                   int* __restrict__ dstn) {
  const int is64 = flag[0];
  int i = blockIdx.x * blockDim.x + threadIdx.x;
  const int stride = gridDim.x * blockDim.x;
  if (is64) {
    const long long* e = (const long long*)eraw;
    for (; i < E; i += stride) {
      srcn[i] = (int)e[i];
      dstn[i] = (int)e[(long long)E + i];
    }
  } else {
    const int* e = (const int*)eraw;
    for (; i < E; i += stride) {
      srcn[i] = e[i];
      dstn[i] = e[E + i];
    }
  }
}

// XCD-partitioned histogram (partition p = blockIdx&7 -> dst range [lo,hi)).
__global__ __launch_bounds__(256) void k_hist(const int* __restrict__ dstn, int E,
                                              int N, int* __restrict__ counts) {
  const int part = blockIdx.x & (PARTS - 1);
  const int lo = (int)((long long)N * part / PARTS);
  const int hi = (int)((long long)N * (part + 1) / PARTS);
  int i = (blockIdx.x >> 3) * blockDim.x + threadIdx.x;
  const int stride = (gridDim.x >> 3) * blockDim.x;
  for (; i < E; i += stride) {
    const int d = dstn[i];
    if (d >= lo && d < hi) atomicAdd(&counts[d], 1);
  }
}

__global__ __launch_bounds__(1024) void k_scan1(const int* __restrict__ counts,
                                                int* __restrict__ scanned,
                                                int* __restrict__ partials, int n) {
  __shared__ int sm[1024];
  const int i = blockIdx.x * 1024 + threadIdx.x;
  const int v = (i < n) ? counts[i] : 0;
  sm[threadIdx.x] = v;
  __syncthreads();
  for (int off = 1; off < 1024; off <<= 1) {
    int t = sm[threadIdx.x];
    int u = (threadIdx.x >= off) ? sm[threadIdx.x - off] : 0;
    __syncthreads();
    sm[threadIdx.x] = t + u;
    __syncthreads();
  }
  const int inc = sm[threadIdx.x];
  if (i < n) scanned[i] = inc - v;  // exclusive within block
  if (threadIdx.x == 1023) partials[blockIdx.x] = inc;  // block total
}

__global__ __launch_bounds__(256) void k_scan3(const int* __restrict__ scanned,
                                               const int* __restrict__ partials,
                                               int nb,
                                               const int* __restrict__ counts,
                                               int* __restrict__ offsets,
                                               int* __restrict__ cursor,
                                               float* __restrict__ dinv, int n) {
  __shared__ int ps[1024];
  for (int t = threadIdx.x; t < nb; t += 256) ps[t] = partials[t];
  __syncthreads();
  if (threadIdx.x == 0) {
    int run = 0;
    for (int b = 0; b < nb; ++b) { const int v = ps[b]; ps[b] = run; run += v; }
  }
  __syncthreads();
  int i = blockIdx.x * blockDim.x + threadIdx.x;
  const int stride = gridDim.x * blockDim.x;
  for (; i < n; i += stride) {
    const int o = scanned[i] + ps[i >> 10];
    offsets[i] = o;
    cursor[i] = o;
    dinv[i] = rsqrtf((float)counts[i] + 1.0f);  // +1 self-loop
  }
}

// XCD-partitioned fill.
__global__ __launch_bounds__(256) void k_fill(const int* __restrict__ srcn,
                                              const int* __restrict__ dstn, int E,
                                              int N, int* __restrict__ cursor,
                                              int* __restrict__ elist) {
  const int part = blockIdx.x & (PARTS - 1);
  const int lo = (int)((long long)N * part / PARTS);
  const int hi = (int)((long long)N * (part + 1) / PARTS);
  int i = (blockIdx.x >> 3) * blockDim.x + threadIdx.x;
  const int stride = (gridDim.x >> 3) * blockDim.x;
  for (; i < E; i += stride) {
    const int d = dstn[i];
    if (d >= lo && d < hi) elist[atomicAdd(&cursor[d], 1)] = srcn[i];
  }
}

// hs = dinv .* (X @ W) via bf16-split MFMA (R11-proven).
template <int F_IN, int F_OUT>
__global__ __launch_bounds__(256) void k_transform_mfma(
    const float* __restrict__ X, const short* __restrict__ Wh,
    const short* __restrict__ Wl, const float* __restrict__ dinv,
    float* __restrict__ H, int n) {
  constexpr int KT = F_IN / 32;
  constexpr int NT = F_OUT / 16;
  constexpr int K4f = F_IN / 4;
  constexpr int SLOTS = F_IN / 8;
  constexpr int TILE_M = 64;
  constexpr int WFRAG = KT * NT * 64 * 8;
  static_assert((WFRAG * 2) % 1024 == 0, "W segs");

  __shared__ __align__(16) unsigned short Xh[TILE_M * F_IN];
  __shared__ __align__(16) unsigned short Xl[TILE_M * F_IN];
  __shared__ __align__(16) unsigned short Whs[WFRAG];
  __shared__ __align__(16) unsigned short Wls[WFRAG];

  const int tid = threadIdx.x;
  const int lane = tid & 63;
  const int wid = tid >> 6;
  const long long base = (long long)blockIdx.x * TILE_M;

  constexpr int WSEGS = WFRAG * 2 / 1024;
  for (int seg = wid; seg < WSEGS; seg += 4) {
    gld16((const char*)Wh + seg * 1024 + lane * 16, (char*)Whs + seg * 1024);
    gld16((const char*)Wl + seg * 1024 + lane * 16, (char*)Wls + seg * 1024);
  }

  const float4* __restrict__ X4 = (const float4*)X;
  for (int g = tid; g < TILE_M * K4f; g += 256) {
    const int row = g / K4f, c4 = g % K4f;
    float4 v = make_float4(0.f, 0.f, 0.f, 0.f);
    if (base + row < n) v = X4[(base + row) * K4f + c4];
    ushort4 hv, lv;
    hv.x = f2bf(v.x); lv.x = f2bf(v.x - bf2f(hv.x));
    hv.y = f2bf(v.y); lv.y = f2bf(v.y - bf2f(hv.y));
    hv.z = f2bf(v.z); lv.z = f2bf(v.z - bf2f(hv.z));
    hv.w = f2bf(v.w); lv.w = f2bf(v.w - bf2f(hv.w));
    const int slot = (c4 >> 1) ^ (row & (SLOTS - 1));
    const int boff = row * (F_IN * 2) + slot * 16 + (c4 & 1) * 8;
    *(ushort4*)((char*)Xh + boff) = hv;
    *(ushort4*)((char*)Xl + boff) = lv;
  }
  __syncthreads();

  const int arow = lane & 15;
  const int kg = lane >> 4;
  const int lrow = wid * 16 + arow;

  f32x4 acc[NT];
  #pragma unroll
  for (int t = 0; t < NT; ++t) {
    f32x4 z = {0.f, 0.f, 0.f, 0.f};
    acc[t] = z;
  }

  #pragma unroll
  for (int kt = 0; kt < KT; ++kt) {
    const int slot = (kt * 4 + kg) ^ (lrow & (SLOTS - 1));
    const int aoff = lrow * (F_IN * 2) + slot * 16;
    const bf16x8 ah = *(const bf16x8*)((const char*)Xh + aoff);
    const bf16x8 al = *(const bf16x8*)((const char*)Xl + aoff);
    #pragma unroll
    for (int nt = 0; nt < NT; ++nt) {
      const int woff = ((kt * NT + nt) * 64 + lane) * 8;
      const bf16x8 bh = *(const bf16x8*)&Whs[woff];
      const bf16x8 bl = *(const bf16x8*)&Wls[woff];
      acc[nt] = __builtin_amdgcn_mfma_f32_16x16x32_bf16(ah, bh, acc[nt], 0, 0, 0);
      acc[nt] = __builtin_amdgcn_mfma_f32_16x16x32_bf16(ah, bl, acc[nt], 0, 0, 0);
      acc[nt] = __builtin_amdgcn_mfma_f32_16x16x32_bf16(al, bh, acc[nt], 0, 0, 0);
    }
  }

  #pragma unroll
  for (int r = 0; r < 4; ++r) {
    const long long row = base + wid * 16 + kg * 4 + r;
    if (row < n) {
      const float di = dinv[row];
      #pragma unroll
      for (int nt = 0; nt < NT; ++nt)
        H[row * F_OUT + nt * 16 + arow] = di * acc[nt][r];
    }
  }
}

// Edge-group-parallel aggregate, TWO nodes per wave (dA, dB = dA + nwaves):
// 4 independent gathers in flight. LPE=F/4 lanes/edge, EPW=64/LPE edges/instr.
// out[d][:] = relu?(b + dinv[d]*(hs[d] + sum_s hs[s]))
// FUSE_W3: instead writes hs3 = dinv .* (relu(out2) @ W3)  (2 floats).
template <int F, bool RELU_OUT, bool FUSE_W3>
__global__ __launch_bounds__(256) void k_agg_vec2(const float* __restrict__ HS,
                                                  const float* __restrict__ dinv,
                                                  const int* __restrict__ offsets,
                                                  const int* __restrict__ counts,
                                                  const int* __restrict__ elist,
                                                  const float* __restrict__ bias,
                                                  const float* __restrict__ W3,
                                                  float* __restrict__ out, int n) {
  constexpr int LPE = F / 4;
  constexpr int EPW = 64 / LPE;
  const int lane = threadIdx.x & 63;
  const int wv = (blockIdx.x * (blockDim.x >> 6)) + (threadIdx.x >> 6);
  const int nwaves = gridDim.x * (blockDim.x >> 6);
  const int g = lane / LPE;
  const int fl = lane % LPE;
  const float4 bf = *(const float4*)&bias[fl * 4];

  float w3a0 = 0.f, w3a1 = 0.f, w3a2 = 0.f, w3a3 = 0.f;
  float w3b0 = 0.f, w3b1 = 0.f, w3b2 = 0.f, w3b3 = 0.f;
  if (FUSE_W3) {
    w3a0 = W3[(fl * 4 + 0) * 2 + 0]; w3b0 = W3[(fl * 4 + 0) * 2 + 1];
    w3a1 = W3[(fl * 4 + 1) * 2 + 0]; w3b1 = W3[(fl * 4 + 1) * 2 + 1];
    w3a2 = W3[(fl * 4 + 2) * 2 + 0]; w3b2 = W3[(fl * 4 + 2) * 2 + 1];
    w3a3 = W3[(fl * 4 + 3) * 2 + 0]; w3b3 = W3[(fl * 4 + 3) * 2 + 1];
  }

  for (long long dA = wv; dA < n; dA += 2ll * nwaves) {
    const long long dB = dA + nwaves;
    const bool hasB = dB < n;
    const float diA = dinv[dA];
    const float diB = hasB ? dinv[dB] : 0.f;
    const int stA = offsets[dA];
    const int cntA = counts[dA];
    const int stB = hasB ? offsets[dB] : 0;
    const int cntB = hasB ? counts[dB] : 0;
    float4 accA = make_float4(0.f, 0.f, 0.f, 0.f);
    float4 accB = make_float4(0.f, 0.f, 0.f, 0.f);
    if (g == 0) accA = *(const float4*)&HS[dA * F + fl * 4];  // self A
    if (g == 1 && hasB) accB = *(const float4*)&HS[dB * F + fl * 4];  // self B

    const int jmax = cntA > cntB ? cntA : cntB;
    const int cA = cntA > 0 ? cntA - 1 : 0;
    const int cB = cntB > 0 ? cntB - 1 : 0;
    for (int j = 0; j < jmax; j += 2 * EPW) {
      const int e0 = j + g;
      const int e1 = j + EPW + g;
      const int iA0 = elist[stA + (e0 < cntA ? e0 : cA)];
      const int iA1 = elist[stA + (e1 < cntA ? e1 : cA)];
      const int iB0 = elist[stB + (e0 < cntB ? e0 : cB)];
      const int iB1 = elist[stB + (e1 < cntB ? e1 : cB)];
      const float4 vA0 = *(const float4*)&HS[(long long)iA0 * F + fl * 4];
      const float4 vA1 = *(const float4*)&HS[(long long)iA1 * F + fl * 4];
      const float4 vB0 = *(const float4*)&HS[(long long)iB0 * F + fl * 4];
      const float4 vB1 = *(const float4*)&HS[(long long)iB1 * F + fl * 4];
      if (e0 < cntA) {
        accA.x += vA0.x; accA.y += vA0.y; accA.z += vA0.z; accA.w += vA0.w;
      }
      if (e1 < cntA) {
        accA.x += vA1.x; accA.y += vA1.y; accA.z += vA1.z; accA.w += vA1.w;
      }
      if (e0 < cntB) {
        accB.x += vB0.x; accB.y += vB0.y; accB.z += vB0.z; accB.w += vB0.w;
      }
      if (e1 < cntB) {
        accB.x += vB1.x; accB.y += vB1.y; accB.z += vB1.z; accB.w += vB1.w;
      }
    }
    // reduce across edge groups
    #pragma unroll
    for (int m = LPE; m < 64; m <<= 1) {
      accA.x += __shfl_xor(accA.x, m, 64);
      accA.y += __shfl_xor(accA.y, m, 64);
      accA.z += __shfl_xor(accA.z, m, 64);
      accA.w += __shfl_xor(accA.w, m, 64);
      accB.x += __shfl_xor(accB.x, m, 64);
      accB.y += __shfl_xor(accB.y, m, 64);
      accB.z += __shfl_xor(accB.z, m, 64);
      accB.w += __shfl_xor(accB.w, m, 64);
    }
    float4 rA, rB;
    rA.x = fmaf(diA, accA.x, bf.x); rA.y = fmaf(diA, accA.y, bf.y);
    rA.z = fmaf(diA, accA.z, bf.z); rA.w = fmaf(diA, accA.w, bf.w);
    rB.x = fmaf(diB, accB.x, bf.x); rB.y = fmaf(diB, accB.y, bf.y);
    rB.z = fmaf(diB, accB.z, bf.z); rB.w = fmaf(diB, accB.w, bf.w);
    if (RELU_OUT) {
      rA.x = fmaxf(rA.x, 0.f); rA.y = fmaxf(rA.y, 0.f);
      rA.z = fmaxf(rA.z, 0.f); rA.w = fmaxf(rA.w, 0.f);
      rB.x = fmaxf(rB.x, 0.f); rB.y = fmaxf(rB.y, 0.f);
      rB.z = fmaxf(rB.z, 0.f); rB.w = fmaxf(rB.w, 0.f);
    }
    if (!FUSE_W3) {
      if (g == 0) *(float4*)&out[dA * F + fl * 4] = rA;
      if (g == 1 && hasB) *(float4*)&out[dB * F + fl * 4] = rB;
    } else {
      float tA0 = rA.x * w3a0 + rA.y * w3a1 + rA.z * w3a2 + rA.w * w3a3;
      float tA1 = rA.x * w3b0 + rA.y * w3b1 + rA.z * w3b2 + rA.w * w3b3;
      float tB0 = rB.x * w3a0 + rB.y * w3a1 + rB.z * w3a2 + rB.w * w3a3;
      float tB1 = rB.x * w3b0 + rB.y * w3b1 + rB.z * w3b2 + rB.w * w3b3;
      #pragma unroll
      for (int m = 1; m < LPE; m <<= 1) {
        tA0 += __shfl_xor(tA0, m, 64);
        tA1 += __shfl_xor(tA1, m, 64);
        tB0 += __shfl_xor(tB0, m, 64);
        tB1 += __shfl_xor(tB1, m, 64);
      }
      if (lane == 0) {
        out[dA * 2 + 0] = diA * tA0;
        out[dA * 2 + 1] = diA * tA1;
      }
      if (lane == LPE && hasB) {
        out[dB * 2 + 0] = diB * tB0;
        out[dB * 2 + 1] = diB * tB1;
      }
    }
  }
}

// scalar aggregate for tiny F (layer 3, F=2)
template <int F, bool RELU_OUT>
__global__ __launch_bounds__(256) void k_aggregate(const float* __restrict__ HS,
                                                   const float* __restrict__ dinv,
                                                   const int* __restrict__ offsets,
                                                   const int* __restrict__ counts,
                                                   const int* __restrict__ elist,
                                                   const float* __restrict__ bias,
                                                   float* __restrict__ out, int n) {
  const int f = threadIdx.x % F;
  const int grp = threadIdx.x / F;
  constexpr int GRPS = 256 / F;
  const float bf = bias[f];

  for (long long d = (long long)blockIdx.x * GRPS + grp; d < n;
       d += (long long)gridDim.x * GRPS) {
    const float di = dinv[d];
    float acc = HS[d * F + f];
    const int start = offsets[d];
    const int cnt = counts[d];
    for (int j = 0; j < cnt; j += 8) {
      int idx[8];
      float v[8];
      #pragma unroll
      for (int t = 0; t < 8; ++t) {
        const int jj = (j + t < cnt) ? (j + t) : j;
        idx[t] = elist[start + jj];
      }
      #pragma unroll
      for (int t = 0; t < 8; ++t) v[t] = HS[(long long)idx[t] * F + f];
      #pragma unroll
      for (int t = 0; t < 8; ++t) acc += (j + t < cnt) ? v[t] : 0.f;
    }
    float r = fmaf(di, acc, bf);
    if (RELU_OUT) r = fmaxf(r, 0.f);
    out[d * F + f] = r;
  }
}

extern "C" void kernel_launch(void* const* d_in, const int* in_sizes, int n_in,
                              void* d_out, int out_size, void* d_ws, size_t ws_size,
                              hipStream_t stream) {
  const float* x = (const float*)d_in[0];
  const void* eraw = d_in[1];
  const float* W1 = (const float*)d_in[2];
  const float* b1 = (const float*)d_in[3];
  const float* W2 = (const float*)d_in[4];
  const float* b2 = (const float*)d_in[5];
  const float* W3 = (const float*)d_in[6];
  const float* b3 = (const float*)d_in[7];
  float* out = (float*)d_out;

  const int N = in_sizes[0] / 128;  // 100000
  const int E = in_sizes[1] / 2;    // 600000

  char* ws = (char*)d_ws;
  size_t off = 0;
  auto alloc = [&](size_t bytes) -> char* {
    char* p = ws + off;
    off = (off + bytes + 255) & ~(size_t)255;
    return p;
  };
  int*   flag     = (int*)alloc(256);
  int*   counts   = (int*)alloc((size_t)N * 4 + 16);
  int*   scanned  = (int*)alloc((size_t)N * 4);
  int*   partials = (int*)alloc(1024 * 4);
  int*   offsets  = (int*)alloc((size_t)N * 4);
  int*   cursor   = (int*)alloc((size_t)N * 4);
  int*   srcn     = (int*)alloc((size_t)E * 4);
  int*   dstn     = (int*)alloc((size_t)E * 4);
  int*   elist    = (int*)alloc((size_t)E * 4);
  float* dinv     = (float*)alloc((size_t)N * 4);
  short* Wh1      = (short*)alloc(4 * 4 * 64 * 8 * 2);
  short* Wl1      = (short*)alloc(4 * 4 * 64 * 8 * 2);
  short* Wh2      = (short*)alloc(2 * 2 * 64 * 8 * 2);
  short* Wl2      = (short*)alloc(2 * 2 * 64 * 8 * 2);
  float* hbuf     = (float*)alloc((size_t)N * 64 * 4);  // hs1; later hs3 [N,2]
  float* obuf     = (float*)alloc((size_t)N * 64 * 4);  // out1 [N,64]
  float* h2buf    = (float*)alloc((size_t)N * 32 * 4);  // hs2 [N,32]
  (void)ws_size; (void)n_in; (void)out_size;

  // ---- CSR build + W pre-pack ----
  k_init<<<161, 256, 0, stream>>>(counts, (N + 3) / 4, (const unsigned int*)eraw,
                                  flag, W1, W2, Wh1, Wl1, Wh2, Wl2);
  k_normalize<<<1024, 256, 0, stream>>>(eraw, E, flag, srcn, dstn);
  k_hist<<<FULL_GRID, 256, 0, stream>>>(dstn, E, N, counts);
  const int NB = (N + 1023) >> 10;
  k_scan1<<<NB, 1024, 0, stream>>>(counts, scanned, partials, N);
  k_scan3<<<(N + 255) / 256, 256, 0, stream>>>(scanned, partials, NB, counts,
                                               offsets, cursor, dinv, N);
  k_fill<<<FULL_GRID, 256, 0, stream>>>(srcn, dstn, E, N, cursor, elist);

  // ---- layer 1: hs1 = dinv.*(x@W1); out1 = relu(agg(hs1)) ----
  k_transform_mfma<128, 64><<<(N + 63) / 64, 256, 0, stream>>>(
      x, Wh1, Wl1, dinv, hbuf, N);
  k_agg_vec2<64, true, false><<<FULL_GRID, 256, 0, stream>>>(
      hbuf, dinv, offsets, counts, elist, b1, nullptr, obuf, N);

  // ---- layer 2: hs2 = dinv.*(out1@W2); agg + ReLU + fused W3 -> hs3 ----
  k_transform_mfma<64, 32><<<(N + 63) / 64, 256, 0, stream>>>(
      obuf, Wh2, Wl2, dinv, h2buf, N);
  k_agg_vec2<32, true, true><<<FULL_GRID, 256, 0, stream>>>(
      h2buf, dinv, offsets, counts, elist, b2, W3, hbuf, N);

  // ---- layer 3: agg hs3 + ReLU -> out ----
  k_aggregate<2, true><<<(N + 127) / 128, 256, 0, stream>>>(
      hbuf, dinv, offsets, counts, elist, b3, out, N);
}